// Round 1
// baseline (850.578 us; speedup 1.0000x reference)
//
#include <hip/hip_runtime.h>

// Problem constants (fixed by the reference setup)
#define DIN   128
#define DMID  256
#define DOUT  128
#define KTOT  384      // DIN + DMID
#define VNUM  50000

typedef __attribute__((ext_vector_type(8))) __bf16 bf16x8;
typedef __attribute__((ext_vector_type(4))) float  f32x4;

// order-preserving float -> uint map (monotone for all non-NaN floats)
static __device__ __forceinline__ unsigned flipf(float f) {
  unsigned u = __float_as_uint(f);
  return u ^ ((unsigned)((int)u >> 31) | 0x80000000u);
}
// inverse map, returning raw f32 bits
static __device__ __forceinline__ unsigned unflip_bits(unsigned m) {
  unsigned mask = ((int)m < 0) ? 0x80000000u : 0xFFFFFFFFu;
  return m ^ mask;
}
// f32 bits -> bf16 bits, round-to-nearest-even
static __device__ __forceinline__ unsigned short f2b_bits(unsigned b) {
  return (unsigned short)((b + 0x7FFFu + ((b >> 16) & 1u)) >> 16);
}
static __device__ __forceinline__ unsigned short f2b(float f) {
  return f2b_bits(__float_as_uint(f));
}

// ---------------------------------------------------------------------------
// Kernel 1: z = x @ W1 + b1   (bf16 MFMA), then scatter-max into zu (flipped
// uint). Block = 256 thr (4 waves). Tile: 64 edges x 256 cols. W1 fragments
// and bias live in registers (per-wave 64-col slice); x tile staged in LDS.
// ---------------------------------------------------------------------------
__global__ __launch_bounds__(256) void k_gemm1_scatter(
    const float* __restrict__ x, const int* __restrict__ vid,
    const float* __restrict__ W1, const float* __restrict__ b1,
    unsigned* __restrict__ zu, int ntiles) {
  // pad 128 -> 136 bf16 per row (272B stride -> 4-bank rotation, 2-way max)
  __shared__ unsigned short lx[64 * 136];
  __shared__ int lvid[64];

  const int tid  = threadIdx.x;
  const int lane = tid & 63;
  const int w    = tid >> 6;       // wave id 0..3 -> col slice w*64
  const int l15  = lane & 15;
  const int l4   = lane >> 4;

  // Preload W1 fragments for this wave's 64 columns: [kk][ni], plus bias.
  bf16x8 bfrag[4][4];
  float  bias[4];
#pragma unroll
  for (int ni = 0; ni < 4; ++ni) {
    const int col = w * 64 + ni * 16 + l15;
    bias[ni] = b1[col];
#pragma unroll
    for (int kk = 0; kk < 4; ++kk) {
      union { bf16x8 v; unsigned short u[8]; } tmp;
#pragma unroll
      for (int j = 0; j < 8; ++j) {
        const int k = kk * 32 + l4 * 8 + j;
        tmp.u[j] = f2b(W1[k * DMID + col]);
      }
      bfrag[kk][ni] = tmp.v;
    }
  }

  for (int t = blockIdx.x; t < ntiles; t += gridDim.x) {
    // ---- stage x tile (64 x 128 f32 -> bf16 LDS) + vertex ids ----
    {
      const int row = tid >> 2, q = tid & 3;
      const float4* src =
          reinterpret_cast<const float4*>(x + (size_t)(t * 64 + row) * DIN + q * 32);
      unsigned short* dst = &lx[row * 136 + q * 32];
#pragma unroll
      for (int i = 0; i < 8; ++i) {
        float4 v = src[i];
        ushort4 o = { f2b(v.x), f2b(v.y), f2b(v.z), f2b(v.w) };
        *reinterpret_cast<ushort4*>(dst + i * 4) = o;
      }
      if (tid < 64) lvid[tid] = vid[t * 64 + tid];
    }
    __syncthreads();

    // ---- MFMA: 64x64 per wave, K=128 ----
    f32x4 acc[4][4];
#pragma unroll
    for (int mi = 0; mi < 4; ++mi)
#pragma unroll
      for (int ni = 0; ni < 4; ++ni)
        acc[mi][ni] = (f32x4){bias[ni], bias[ni], bias[ni], bias[ni]};

#pragma unroll
    for (int kk = 0; kk < 4; ++kk) {
      bf16x8 a[4];
#pragma unroll
      for (int mi = 0; mi < 4; ++mi)
        a[mi] = *reinterpret_cast<const bf16x8*>(
            &lx[(mi * 16 + l15) * 136 + kk * 32 + l4 * 8]);
#pragma unroll
      for (int mi = 0; mi < 4; ++mi)
#pragma unroll
        for (int ni = 0; ni < 4; ++ni)
          acc[mi][ni] = __builtin_amdgcn_mfma_f32_16x16x32_bf16(
              a[mi], bfrag[kk][ni], acc[mi][ni], 0, 0, 0);
    }

    // ---- epilogue: flipped-uint atomicMax scatter ----
#pragma unroll
    for (int mi = 0; mi < 4; ++mi) {
#pragma unroll
      for (int r = 0; r < 4; ++r) {
        const int row = mi * 16 + l4 * 4 + r;
        const int v   = lvid[row];
        unsigned* base = zu + (size_t)v * DMID + w * 64 + l15;
#pragma unroll
        for (int ni = 0; ni < 4; ++ni)
          atomicMax(base + ni * 16, flipf(acc[mi][ni][r]));
      }
    }
    __syncthreads();
  }
}

// ---------------------------------------------------------------------------
// Kernel 2: out = [x | unflip(zu[vid])] @ W2   (bf16 MFMA, fp32 out).
// Block = 256 thr (4 waves, wave grid 2x2: 32 rows x 64 cols each).
// W2^T staged once per block in dynamic LDS [128][392]; A tile [64][392].
// ---------------------------------------------------------------------------
__global__ __launch_bounds__(256) void k_gemm2(
    const float* __restrict__ x, const int* __restrict__ vid,
    const float* __restrict__ W2, const unsigned* __restrict__ zu,
    float* __restrict__ out, int ntiles) {
  extern __shared__ unsigned short sm[];
  unsigned short* w2t = sm;                 // [128][392] bf16
  unsigned short* la  = sm + 128 * 392;     // [64][392]  bf16

  const int tid  = threadIdx.x;
  const int lane = tid & 63;
  const int w    = tid >> 6;
  const int wr   = w >> 1;                  // 0..1 row-group (32 rows)
  const int wc   = w & 1;                   // 0..1 col-group (64 cols)
  const int l15  = lane & 15;
  const int l4   = lane >> 4;

  // ---- stage W2^T once per block ----
  {
    const int n = tid & 127, kh = tid >> 7;
    for (int k = kh * 192; k < kh * 192 + 192; ++k)
      w2t[n * 392 + k] = f2b(W2[(size_t)k * DOUT + n]);
  }
  __syncthreads();

  for (int t = blockIdx.x; t < ntiles; t += gridDim.x) {
    // ---- stage A = [x | gathered z_max] as bf16 ----
    {
      const int row = tid >> 2, q = tid & 3;
      const float4* sx =
          reinterpret_cast<const float4*>(x + (size_t)(t * 64 + row) * DIN + q * 32);
      unsigned short* dx = &la[row * 392 + q * 32];
#pragma unroll
      for (int i = 0; i < 8; ++i) {
        float4 v = sx[i];
        ushort4 o = { f2b(v.x), f2b(v.y), f2b(v.z), f2b(v.w) };
        *reinterpret_cast<ushort4*>(dx + i * 4) = o;
      }
      const int vv = vid[t * 64 + row];
      const uint4* sz =
          reinterpret_cast<const uint4*>(zu + (size_t)vv * DMID + q * 64);
      unsigned short* dz = &la[row * 392 + DIN + q * 64];
#pragma unroll
      for (int i = 0; i < 16; ++i) {
        uint4 m = sz[i];
        ushort4 o = { f2b_bits(unflip_bits(m.x)), f2b_bits(unflip_bits(m.y)),
                      f2b_bits(unflip_bits(m.z)), f2b_bits(unflip_bits(m.w)) };
        *reinterpret_cast<ushort4*>(dz + i * 4) = o;
      }
    }
    __syncthreads();

    // ---- MFMA: 32x64 per wave, K=384 ----
    f32x4 acc[2][4];
#pragma unroll
    for (int mi = 0; mi < 2; ++mi)
#pragma unroll
      for (int ni = 0; ni < 4; ++ni)
        acc[mi][ni] = (f32x4){0.f, 0.f, 0.f, 0.f};

#pragma unroll
    for (int kk = 0; kk < 12; ++kk) {
      bf16x8 a[2], b[4];
#pragma unroll
      for (int mi = 0; mi < 2; ++mi)
        a[mi] = *reinterpret_cast<const bf16x8*>(
            &la[(wr * 32 + mi * 16 + l15) * 392 + kk * 32 + l4 * 8]);
#pragma unroll
      for (int ni = 0; ni < 4; ++ni)
        b[ni] = *reinterpret_cast<const bf16x8*>(
            &w2t[(wc * 64 + ni * 16 + l15) * 392 + kk * 32 + l4 * 8]);
#pragma unroll
      for (int mi = 0; mi < 2; ++mi)
#pragma unroll
        for (int ni = 0; ni < 4; ++ni)
          acc[mi][ni] = __builtin_amdgcn_mfma_f32_16x16x32_bf16(
              a[mi], b[ni], acc[mi][ni], 0, 0, 0);
    }

    // ---- store fp32 ----
#pragma unroll
    for (int mi = 0; mi < 2; ++mi)
#pragma unroll
      for (int r = 0; r < 4; ++r) {
        const int row = wr * 32 + mi * 16 + l4 * 4 + r;
        float* o = out + (size_t)(t * 64 + row) * DOUT + wc * 64 + l15;
#pragma unroll
        for (int ni = 0; ni < 4; ++ni) o[ni * 16] = acc[mi][ni][r];
      }
    __syncthreads();
  }
}

// ---------------------------------------------------------------------------
extern "C" void kernel_launch(void* const* d_in, const int* in_sizes, int n_in,
                              void* d_out, int out_size, void* d_ws, size_t ws_size,
                              hipStream_t stream) {
  const float* x   = (const float*)d_in[0];
  const int*   vid = (const int*)d_in[1];
  const float* W1  = (const float*)d_in[2];
  const float* b1  = (const float*)d_in[3];
  const float* W2  = (const float*)d_in[4];
  float* out = (float*)d_out;

  const int E = in_sizes[1];          // 800000, divisible by 64
  const int ntiles = E / 64;
  unsigned* zu = (unsigned*)d_ws;     // V x DMID flipped-uint max buffer

  // zero-init scatter-max buffer (0 == flipped(-NaN), below every real value)
  hipMemsetAsync(zu, 0, (size_t)VNUM * DMID * sizeof(unsigned), stream);

  k_gemm1_scatter<<<512, 256, 0, stream>>>(x, vid, W1, b1, zu, ntiles);

  const int smem2 = (128 * 392 + 64 * 392) * sizeof(unsigned short); // 150528 B
  hipFuncSetAttribute((const void*)k_gemm2,
                      hipFuncAttributeMaxDynamicSharedMemorySize, smem2);
  k_gemm2<<<256, 256, smem2, stream>>>(x, vid, W2, zu, out, ntiles);
}

// Round 2
// 618.984 us; speedup vs baseline: 1.3742x; 1.3742x over previous
//
#include <hip/hip_runtime.h>

#define DIN   128
#define DMID  256
#define DOUT  128
#define VNUM  50000

typedef __attribute__((ext_vector_type(8))) __bf16 bf16x8;
typedef __attribute__((ext_vector_type(4))) float  f32x4;

// ---- order-preserving monotone maps ----
static __device__ __forceinline__ unsigned flipf(float f) {
  unsigned u = __float_as_uint(f);
  return u ^ ((unsigned)((int)u >> 31) | 0x80000000u);
}
static __device__ __forceinline__ unsigned unflip_bits(unsigned m) {
  unsigned mask = ((int)m < 0) ? 0x80000000u : 0xFFFFFFFFu;
  return m ^ mask;
}
// bf16 bits -> flipped u16 (monotone in float order)
static __device__ __forceinline__ unsigned short flip16(unsigned short b) {
  return b ^ (unsigned short)(((short)b >> 15) | 0x8000);
}
// flipped u16 -> flipped u32 of the same bf16 value widened to f32
// (positive originals: low bits 0; negative originals: low bits 0xFFFF)
static __device__ __forceinline__ unsigned flip32_from16(unsigned short m) {
  return ((unsigned)m << 16) | ((m & 0x8000u) ? 0u : 0xFFFFu);
}
// f32 bits -> bf16 bits, round-to-nearest-even
static __device__ __forceinline__ unsigned short f2b_bits(unsigned b) {
  return (unsigned short)((b + 0x7FFFu + ((b >> 16) & 1u)) >> 16);
}
static __device__ __forceinline__ unsigned short f2b(float f) {
  return f2b_bits(__float_as_uint(f));
}

// ---------------------------------------------------------------------------
// Sort machinery: histogram -> exclusive scan (cursor) -> scatter sorted ids
// ---------------------------------------------------------------------------
__global__ void k_hist(const int* __restrict__ vid, int* __restrict__ counts, int E) {
  int i = blockIdx.x * blockDim.x + threadIdx.x;
  if (i < E) atomicAdd(counts + vid[i], 1);
}

__global__ __launch_bounds__(1024) void k_scan(int* __restrict__ cursor, int V) {
  // in-place exclusive scan over counts (cursor aliases counts)
  __shared__ int wsum[16];
  const int tid = threadIdx.x, lane = tid & 63, wv = tid >> 6;
  int carry = 0;
  for (int base = 0; base < V; base += 1024) {
    const int idx = base + tid;
    const int c = (idx < V) ? cursor[idx] : 0;
    int s = c;  // inclusive wave scan
#pragma unroll
    for (int d = 1; d < 64; d <<= 1) {
      int t = __shfl_up(s, d, 64);
      if (lane >= d) s += t;
    }
    if (lane == 63) wsum[wv] = s;
    __syncthreads();
    if (wv == 0 && lane < 16) {
      int ws = wsum[lane];
#pragma unroll
      for (int d = 1; d < 16; d <<= 1) {
        int t = __shfl_up(ws, d, 16);
        if (lane >= d) ws += t;
      }
      wsum[lane] = ws;  // inclusive over wave totals
    }
    __syncthreads();
    const int woff = (wv == 0) ? 0 : wsum[wv - 1];
    if (idx < V) cursor[idx] = carry + woff + (s - c);
    carry += wsum[15];
    __syncthreads();
  }
}

__global__ void k_scatter(const int* __restrict__ vid, int* __restrict__ cursor,
                          int* __restrict__ sorted, int E) {
  int i = blockIdx.x * blockDim.x + threadIdx.x;
  if (i < E) {
    int v = vid[i];
    int p = atomicAdd(cursor + v, 1);
    sorted[p] = i;
  }
}

// ---------------------------------------------------------------------------
// Kernel 1: GEMM1 over SORTED edges + in-LDS segmented max + run atomics.
// Block 256 (4 waves), tile = 64 sorted edges x 256 cols; wave owns 64 cols.
// ---------------------------------------------------------------------------
__global__ __launch_bounds__(256, 3) void k_gemm1_max(
    const float* __restrict__ x, const int* __restrict__ vid,
    const int* __restrict__ sorted, const float* __restrict__ W1,
    const float* __restrict__ b1, unsigned* __restrict__ zu, int ntiles) {
  __shared__ unsigned short lx[64 * 136];   // x tile bf16
  __shared__ unsigned short zt[64 * 266];   // z tile, flipped bf16
  __shared__ int lvid[64];
  __shared__ int leid[64];

  const int tid  = threadIdx.x;
  const int lane = tid & 63;
  const int w    = tid >> 6;
  const int l15  = lane & 15;
  const int l4   = lane >> 4;

  // W1 fragments + bias in registers (wave's 64-col slice)
  bf16x8 bfrag[4][4];
  float  bias[4];
#pragma unroll
  for (int ni = 0; ni < 4; ++ni) {
    const int col = w * 64 + ni * 16 + l15;
    bias[ni] = b1[col];
#pragma unroll
    for (int kk = 0; kk < 4; ++kk) {
      union { bf16x8 v; unsigned short u[8]; } tmp;
#pragma unroll
      for (int j = 0; j < 8; ++j)
        tmp.u[j] = f2b(W1[(kk * 32 + l4 * 8 + j) * DMID + col]);
      bfrag[kk][ni] = tmp.v;
    }
  }

  for (int t = blockIdx.x; t < ntiles; t += gridDim.x) {
    if (tid < 64) {
      const int e = sorted[t * 64 + tid];
      leid[tid] = e;
      lvid[tid] = vid[e];
    }
    __syncthreads();

    // stage gathered x rows -> bf16 LDS
    {
      const int row = tid >> 2, q = tid & 3;
      const float4* src =
          reinterpret_cast<const float4*>(x + (size_t)leid[row] * DIN + q * 32);
      unsigned short* dst = &lx[row * 136 + q * 32];
#pragma unroll
      for (int i = 0; i < 8; ++i) {
        float4 v = src[i];
        ushort4 o = { f2b(v.x), f2b(v.y), f2b(v.z), f2b(v.w) };
        *reinterpret_cast<ushort4*>(dst + i * 4) = o;
      }
    }
    __syncthreads();

    // MFMA 64x64 per wave, K=128
    f32x4 acc[4][4];
#pragma unroll
    for (int mi = 0; mi < 4; ++mi)
#pragma unroll
      for (int ni = 0; ni < 4; ++ni)
        acc[mi][ni] = (f32x4){bias[ni], bias[ni], bias[ni], bias[ni]};
#pragma unroll
    for (int kk = 0; kk < 4; ++kk) {
      bf16x8 a[4];
#pragma unroll
      for (int mi = 0; mi < 4; ++mi)
        a[mi] = *reinterpret_cast<const bf16x8*>(
            &lx[(mi * 16 + l15) * 136 + kk * 32 + l4 * 8]);
#pragma unroll
      for (int mi = 0; mi < 4; ++mi)
#pragma unroll
        for (int ni = 0; ni < 4; ++ni)
          acc[mi][ni] = __builtin_amdgcn_mfma_f32_16x16x32_bf16(
              a[mi], bfrag[kk][ni], acc[mi][ni], 0, 0, 0);
    }

    // acc -> zt (flipped bf16)
#pragma unroll
    for (int mi = 0; mi < 4; ++mi)
#pragma unroll
      for (int ni = 0; ni < 4; ++ni)
#pragma unroll
        for (int r = 0; r < 4; ++r) {
          const int row = mi * 16 + l4 * 4 + r;
          const int col = w * 64 + ni * 16 + l15;
          zt[row * 266 + col] = flip16(f2b(acc[mi][ni][r]));
        }
    __syncthreads();

    // segmented column-walk: 256 threads, one col each; runs are uniform
    {
      const int col = tid;
      unsigned short cur = zt[col];
      int curv = lvid[0];
#pragma unroll 4
      for (int rr = 1; rr < 64; ++rr) {
        const unsigned short val = zt[rr * 266 + col];
        const int vv = lvid[rr];
        if (vv != curv) {
          atomicMax(zu + (size_t)curv * DMID + col, flip32_from16(cur));
          curv = vv;
          cur = val;
        } else {
          cur = (val > cur) ? val : cur;
        }
      }
      atomicMax(zu + (size_t)curv * DMID + col, flip32_from16(cur));
    }
    __syncthreads();
  }
}

// ---------------------------------------------------------------------------
// Kernel Y: Y = unflip(zu) @ W2b  (V x 128, f32 out). Block 256, wave 2x2.
// ---------------------------------------------------------------------------
__global__ __launch_bounds__(256) void k_ymm(
    const unsigned* __restrict__ zu, const float* __restrict__ W2,
    float* __restrict__ Y, int ntiles) {
  extern __shared__ unsigned short sm[];
  unsigned short* w2bt = sm;               // [128][264] bf16, [n][k]
  unsigned short* za   = sm + 128 * 264;   // [64][264]  bf16

  const int tid  = threadIdx.x;
  const int lane = tid & 63;
  const int w    = tid >> 6;
  const int wr   = w >> 1, wc = w & 1;
  const int l15  = lane & 15, l4 = lane >> 4;

  {
    const int n = tid & 127, kh = tid >> 7;
    for (int k = kh * 128; k < kh * 128 + 128; ++k)
      w2bt[n * 264 + k] = f2b(W2[(size_t)(DIN + k) * DOUT + n]);
  }
  __syncthreads();

  for (int t = blockIdx.x; t < ntiles; t += gridDim.x) {
    {
      const int row = tid >> 2, q = tid & 3;
      const int v = t * 64 + row;
      unsigned short* dz = &za[row * 264 + q * 64];
      if (v < VNUM) {
        const uint4* sz = reinterpret_cast<const uint4*>(zu + (size_t)v * DMID + q * 64);
#pragma unroll
        for (int i = 0; i < 16; ++i) {
          uint4 m = sz[i];
          ushort4 o = { (unsigned short)(unflip_bits(m.x) >> 16),
                        (unsigned short)(unflip_bits(m.y) >> 16),
                        (unsigned short)(unflip_bits(m.z) >> 16),
                        (unsigned short)(unflip_bits(m.w) >> 16) };
          *reinterpret_cast<ushort4*>(dz + i * 4) = o;
        }
      } else {
        ushort4 zo = {0, 0, 0, 0};
#pragma unroll
        for (int i = 0; i < 16; ++i) *reinterpret_cast<ushort4*>(dz + i * 4) = zo;
      }
    }
    __syncthreads();

    f32x4 acc[2][4];
#pragma unroll
    for (int mi = 0; mi < 2; ++mi)
#pragma unroll
      for (int ni = 0; ni < 4; ++ni) acc[mi][ni] = (f32x4){0.f, 0.f, 0.f, 0.f};

#pragma unroll
    for (int kk = 0; kk < 8; ++kk) {
      bf16x8 a[2], b[4];
#pragma unroll
      for (int mi = 0; mi < 2; ++mi)
        a[mi] = *reinterpret_cast<const bf16x8*>(
            &za[(wr * 32 + mi * 16 + l15) * 264 + kk * 32 + l4 * 8]);
#pragma unroll
      for (int ni = 0; ni < 4; ++ni)
        b[ni] = *reinterpret_cast<const bf16x8*>(
            &w2bt[(wc * 64 + ni * 16 + l15) * 264 + kk * 32 + l4 * 8]);
#pragma unroll
      for (int mi = 0; mi < 2; ++mi)
#pragma unroll
        for (int ni = 0; ni < 4; ++ni)
          acc[mi][ni] = __builtin_amdgcn_mfma_f32_16x16x32_bf16(
              a[mi], b[ni], acc[mi][ni], 0, 0, 0);
    }

#pragma unroll
    for (int mi = 0; mi < 2; ++mi)
#pragma unroll
      for (int r = 0; r < 4; ++r) {
        const int v = t * 64 + wr * 32 + mi * 16 + l4 * 4 + r;
        if (v < VNUM) {
          float* o = Y + (size_t)v * DOUT + wc * 64 + l15;
#pragma unroll
          for (int ni = 0; ni < 4; ++ni) o[ni * 16] = acc[mi][ni][r];
        }
      }
    __syncthreads();
  }
}

// ---------------------------------------------------------------------------
// Kernel 2: out = x @ W2a + Y[vid]  (original edge order). Block 256, wave 2x2.
// ---------------------------------------------------------------------------
__global__ __launch_bounds__(256, 3) void k_gemm2(
    const float* __restrict__ x, const int* __restrict__ vid,
    const float* __restrict__ W2, const float* __restrict__ Y,
    float* __restrict__ out, int ntiles) {
  __shared__ unsigned short w2at[128 * 136];  // [n][k] bf16
  __shared__ unsigned short lx[64 * 136];
  __shared__ int lvid[64];

  const int tid  = threadIdx.x;
  const int lane = tid & 63;
  const int w    = tid >> 6;
  const int wr   = w >> 1, wc = w & 1;
  const int l15  = lane & 15, l4 = lane >> 4;

  {
    const int n = tid & 127, kh = tid >> 7;
    for (int k = kh * 64; k < kh * 64 + 64; ++k)
      w2at[n * 136 + k] = f2b(W2[(size_t)k * DOUT + n]);
  }
  __syncthreads();

  for (int t = blockIdx.x; t < ntiles; t += gridDim.x) {
    {
      const int row = tid >> 2, q = tid & 3;
      const float4* sx =
          reinterpret_cast<const float4*>(x + (size_t)(t * 64 + row) * DIN + q * 32);
      unsigned short* dx = &lx[row * 136 + q * 32];
#pragma unroll
      for (int i = 0; i < 8; ++i) {
        float4 v = sx[i];
        ushort4 o = { f2b(v.x), f2b(v.y), f2b(v.z), f2b(v.w) };
        *reinterpret_cast<ushort4*>(dx + i * 4) = o;
      }
      if (tid < 64) lvid[tid] = vid[t * 64 + tid];
    }
    __syncthreads();

    f32x4 acc[2][4];
#pragma unroll
    for (int mi = 0; mi < 2; ++mi)
#pragma unroll
      for (int ni = 0; ni < 4; ++ni) acc[mi][ni] = (f32x4){0.f, 0.f, 0.f, 0.f};

#pragma unroll
    for (int kk = 0; kk < 4; ++kk) {
      bf16x8 a[2], b[4];
#pragma unroll
      for (int mi = 0; mi < 2; ++mi)
        a[mi] = *reinterpret_cast<const bf16x8*>(
            &lx[(wr * 32 + mi * 16 + l15) * 136 + kk * 32 + l4 * 8]);
#pragma unroll
      for (int ni = 0; ni < 4; ++ni)
        b[ni] = *reinterpret_cast<const bf16x8*>(
            &w2at[(wc * 64 + ni * 16 + l15) * 136 + kk * 32 + l4 * 8]);
#pragma unroll
      for (int mi = 0; mi < 2; ++mi)
#pragma unroll
        for (int ni = 0; ni < 4; ++ni)
          acc[mi][ni] = __builtin_amdgcn_mfma_f32_16x16x32_bf16(
              a[mi], b[ni], acc[mi][ni], 0, 0, 0);
    }

    // epilogue: + Y[vid], fp32 store
#pragma unroll
    for (int mi = 0; mi < 2; ++mi)
#pragma unroll
      for (int r = 0; r < 4; ++r) {
        const int row = wr * 32 + mi * 16 + l4 * 4 + r;
        const float* Yr = Y + (size_t)lvid[row] * DOUT + wc * 64 + l15;
        float* o = out + (size_t)(t * 64 + row) * DOUT + wc * 64 + l15;
#pragma unroll
        for (int ni = 0; ni < 4; ++ni) o[ni * 16] = acc[mi][ni][r] + Yr[ni * 16];
      }
    __syncthreads();
  }
}

// ---------------------------------------------------------------------------
extern "C" void kernel_launch(void* const* d_in, const int* in_sizes, int n_in,
                              void* d_out, int out_size, void* d_ws, size_t ws_size,
                              hipStream_t stream) {
  const float* x   = (const float*)d_in[0];
  const int*   vid = (const int*)d_in[1];
  const float* W1  = (const float*)d_in[2];
  const float* b1  = (const float*)d_in[3];
  const float* W2  = (const float*)d_in[4];
  float* out = (float*)d_out;

  const int E = in_sizes[1];      // 800000 (divisible by 64)
  const int ntiles = E / 64;
  const int ntY = (VNUM + 63) / 64;

  // workspace layout
  char* ws = (char*)d_ws;
  unsigned* zu   = (unsigned*)ws;                                   // V*256 u32
  int* cnt       = (int*)(ws + (size_t)VNUM * DMID * 4);            // V (scan in-place -> cursor)
  int* sorted    = (int*)(ws + (size_t)VNUM * DMID * 4 + VNUM * 4); // E
  float* Y       = (float*)(ws + (size_t)VNUM * DMID * 4 + VNUM * 4 + (size_t)E * 4);

  // zero zu + cnt in one shot (0 == flipped bottom for zu)
  hipMemsetAsync(zu, 0, (size_t)VNUM * DMID * 4 + VNUM * 4, stream);

  k_hist<<<(E + 255) / 256, 256, 0, stream>>>(vid, cnt, E);
  k_scan<<<1, 1024, 0, stream>>>(cnt, VNUM);
  k_scatter<<<(E + 255) / 256, 256, 0, stream>>>(vid, cnt, sorted, E);

  k_gemm1_max<<<768, 256, 0, stream>>>(x, vid, sorted, W1, b1, zu, ntiles);

  const int smY = (128 * 264 + 64 * 264) * sizeof(unsigned short); // 101376 B
  hipFuncSetAttribute((const void*)k_ymm,
                      hipFuncAttributeMaxDynamicSharedMemorySize, smY);
  k_ymm<<<256, 256, smY, stream>>>(zu, W2, Y, ntY);

  k_gemm2<<<768, 256, 0, stream>>>(x, vid, W2, Y, out, ntiles);
}